// Round 4
// baseline (376.326 us; speedup 1.0000x reference)
//
#include <hip/hip_runtime.h>
#include <stdint.h>

// Problem shape (fixed by reference): x[4,2048,4096] f32, CB[4096,4096] i8, SCB[4096] f32
static constexpr int Mtot = 8192;   // B*S
static constexpr int Ntot = 4096;   // OUT
static constexpr int Ktot = 4096;   // IN

using i32x4 = __attribute__((ext_vector_type(4))) int;

#define GLD16(gptr, lptr)                                                                   \
  __builtin_amdgcn_global_load_lds((const __attribute__((address_space(1))) void*)(gptr),   \
                                   (__attribute__((address_space(3))) void*)(lptr), 16, 0, 0)
#define WAITVM(N) asm volatile("s_waitcnt vmcnt(" #N ")" ::: "memory")

// ---------------------------------------------------------------------------
// Kernel 1 (fused prep):
//  blocks [0, 16384)      : repack CB int32 -> int8
//  blocks [16384, 24576)  : row-wise dynamic int8 quant of x (one block/row)
// ---------------------------------------------------------------------------
__global__ __launch_bounds__(256) void prep_kernel(const int* __restrict__ cb32,
                                                   int8_t* __restrict__ cb8,
                                                   const float* __restrict__ x,
                                                   int8_t* __restrict__ xq,
                                                   float* __restrict__ sx) {
  __shared__ float wmax[4];
  if (blockIdx.x < 16384) {
    const int idx = blockIdx.x * 256 + threadIdx.x;  // one int4 -> one packed int
    const int4 v = reinterpret_cast<const int4*>(cb32)[idx];
    const unsigned packed = (unsigned)(v.x & 0xff) | ((unsigned)(v.y & 0xff) << 8) |
                            ((unsigned)(v.z & 0xff) << 16) | ((unsigned)(v.w & 0xff) << 24);
    reinterpret_cast<unsigned*>(cb8)[idx] = packed;
    return;
  }
  const int row = blockIdx.x - 16384;
  const float4* xr = reinterpret_cast<const float4*>(x + (size_t)row * Ktot);
  float4 v[4];
  float am = 0.f;
#pragma unroll
  for (int i = 0; i < 4; ++i) {
    v[i] = xr[threadIdx.x + i * 256];
    am = fmaxf(am, fmaxf(fmaxf(fabsf(v[i].x), fabsf(v[i].y)),
                         fmaxf(fabsf(v[i].z), fabsf(v[i].w))));
  }
#pragma unroll
  for (int off = 32; off > 0; off >>= 1) am = fmaxf(am, __shfl_xor(am, off));
  if ((threadIdx.x & 63) == 0) wmax[threadIdx.x >> 6] = am;
  __syncthreads();
  am = fmaxf(fmaxf(wmax[0], wmax[1]), fmaxf(wmax[2], wmax[3]));
  const float inv = 127.0f / am;
  if (threadIdx.x == 0) sx[row] = am * (1.0f / 127.0f);
  unsigned* dq = reinterpret_cast<unsigned*>(xq + (size_t)row * Ktot);
#pragma unroll
  for (int i = 0; i < 4; ++i) {
    const int q0 = (int)rintf(v[i].x * inv);
    const int q1 = (int)rintf(v[i].y * inv);
    const int q2 = (int)rintf(v[i].z * inv);
    const int q3 = (int)rintf(v[i].w * inv);
    dq[threadIdx.x + i * 256] = (unsigned)(q0 & 0xff) | ((unsigned)(q1 & 0xff) << 8) |
                                ((unsigned)(q2 & 0xff) << 16) | ((unsigned)(q3 & 0xff) << 24);
  }
}

// ---------------------------------------------------------------------------
// Kernel 2: int8 GEMM, 256x256 tile, 4-phase pipeline, 2 barriers/tile (r4).
//   Changes vs r3: (1) end-P1 and end-P3 barriers removed — hazard re-derivation
//   shows only end-P0 (gates A1/A3 reads at P1) and end-P2 (gates staging-buf
//   reads at P3 + WAR on buffer swap) are load-bearing; (2) ALL 8 staging loads
//   issued in one burst at P0 (order B0-3, A0, A2, A1, A3), so every load has
//   >=2 phases of cover (A1/A3: 4 phases); (3) A1/A3 gate is the counted
//   WAITVM(8) at end-P0 (8 newer in flight, drains exactly the 2 old ones).
//   Outstanding-count invariant: loop entry = 2 (A1,A3 of cur tile).
//     P0: +8 -> 10; end-P0 WAITVM(8) -> completes A1,A3(cur).
//     end-P2 WAITVM(2) -> completes B0-3,A0,A2(t+1); leaves A1,A3(t+1)=2. ✓
//   vmcnt never 0 in the main loop; peeled last tile drains with WAITVM(0).
//   Phase->compute map (unchanged from r3, frags read one phase ahead):
//     P0: acc[0..3]+=aE(a0-3,k0)*b0 ; read aO(a0-3,k1),b1 ; stage t+1 ; VM8 ; bar
//     P1: acc[0..3]+=aO*b1          ; read aE(a4-7,k0)
//     P2: acc[4..7]+=aE*b0          ; read aO(a4-7,k1)    ; VM2 ; bar
//     P3: acc[4..7]+=aO*b1          ; read aE(a0-3,k0),b0 from staging buf
// ---------------------------------------------------------------------------
__global__ __launch_bounds__(512, 2) void gemm_i8_kernel(const int8_t* __restrict__ A,
                                                         const int8_t* __restrict__ B,
                                                         const float* __restrict__ sx,
                                                         const float* __restrict__ scb,
                                                         float* __restrict__ C) {
  constexpr int BK = 128;
  constexpr int NT = Ktot / BK;  // 32 K-tiles
  __shared__ __align__(16) int8_t lds[131072];

  const int tid = threadIdx.x;
  const int lane = tid & 63;
  const int wid = tid >> 6;

  // T1: XCD-aware swizzle. 512 WGs, 8 XCDs -> each XCD gets 64 consecutive
  // wgids = 4 full m-panel rows (A L2-resident per XCD).
  const int wg = (int)blockIdx.x;
  const int wgs = (wg & 7) * 64 + (wg >> 3);
  const int m0 = (wgs >> 4) * 256;  // 32 m-tiles
  const int n0 = (wgs & 15) * 256;  // 16 n-tiles

  const int wm = (wid >> 2) * 128;  // wave M offset: 0 / 128
  const int wn = (wid & 3) * 64;    // wave N offset: 0/64/128/192

  // Staging: load i covers rows i*64 + tid/8, 16B at column (tid%8)*16,
  // global column inverse-swizzled so the linear LDS write lands swizzled (T2).
  const int srow = tid >> 3;
  const int scol = ((tid & 7) * 16) ^ ((srow & 7) << 4);
  const int8_t* gA = A + (size_t)(m0 + srow) * Ktot + scol;
  const int8_t* gB = B + (size_t)(n0 + srow) * Ktot + scol;

  // Swizzled ds_read offsets. row = w? + f*16 + (lane&15)  =>  row&7 == lane&7.
  const int l15 = lane & 15;
  const int lc0 = ((lane >> 4) * 16) ^ ((lane & 7) << 4);
  const int aOff = (wm + l15) * 128 + lc0;          // + f*2048 ; ^64 for k-half 1
  const int bOff = 65536 + (wn + l15) * 128 + lc0;  // + g*2048 ; ^64 for k-half 1

  i32x4 acc[8][4];
#pragma unroll
  for (int f = 0; f < 8; ++f)
#pragma unroll
    for (int g = 0; g < 4; ++g) acc[f][g] = (i32x4)0;

  // Fragment double-buffer registers (static indices only, rule 20).
  i32x4 aE[4], aO[4], b0v[4], b1v[4];

  // Prologue: stage K-tile 0 into buffer 0, order B0-3, A0, A2, A1, A3.
#pragma unroll
  for (int i = 0; i < 4; ++i) GLD16(gB + (size_t)(i * 64) * Ktot, &lds[65536 + i * 8192 + tid * 16]);
  GLD16(gA + (size_t)(0 * 64) * Ktot, &lds[0 * 8192 + tid * 16]);
  GLD16(gA + (size_t)(2 * 64) * Ktot, &lds[2 * 8192 + tid * 16]);
  GLD16(gA + (size_t)(1 * 64) * Ktot, &lds[1 * 8192 + tid * 16]);
  GLD16(gA + (size_t)(3 * 64) * Ktot, &lds[3 * 8192 + tid * 16]);
  WAITVM(2);  // B + A0,A2 landed; A1,A3 in flight (loop-entry invariant = 2)
  __builtin_amdgcn_s_barrier();
  // Pre-read P0 frags of tile 0 (regions B / A0 / A2 of buf0 — all confirmed).
#pragma unroll
  for (int f = 0; f < 4; ++f) aE[f] = *(const i32x4*)&lds[aOff + f * 2048];
#pragma unroll
  for (int g = 0; g < 4; ++g) b0v[g] = *(const i32x4*)&lds[bOff + g * 2048];

#pragma unroll 2
  for (int t = 0; t < NT - 1; ++t) {
    const int bo = (t & 1) * 32768;  // compute buffer offset
    const int so = bo ^ 32768;       // staging buffer offset
    const size_t kn = (size_t)(t + 1) * BK;

    // ---- P0: read P1 frags (A0/A2 k1 + B k1 of cur — landed long ago);
    //          stage ALL of t+1 (B0-3,A0,A2,A1,A3); MFMA; WAITVM(8); barrier.
    //          WAITVM(8) drains exactly A1,A3(cur) [issued P0(t-1), 4-phase
    //          cover]; barrier makes that a block-wide gate for P1's reads. ----
#pragma unroll
    for (int f = 0; f < 4; ++f) aO[f] = *(const i32x4*)&lds[bo + (aOff ^ 64) + f * 2048];
#pragma unroll
    for (int g = 0; g < 4; ++g) b1v[g] = *(const i32x4*)&lds[bo + (bOff ^ 64) + g * 2048];
#pragma unroll
    for (int i = 0; i < 4; ++i)
      GLD16(gB + kn + (size_t)(i * 64) * Ktot, &lds[65536 + so + i * 8192 + tid * 16]);
    GLD16(gA + kn + (size_t)(0 * 64) * Ktot, &lds[so + 0 * 8192 + tid * 16]);
    GLD16(gA + kn + (size_t)(2 * 64) * Ktot, &lds[so + 2 * 8192 + tid * 16]);
    GLD16(gA + kn + (size_t)(1 * 64) * Ktot, &lds[so + 1 * 8192 + tid * 16]);
    GLD16(gA + kn + (size_t)(3 * 64) * Ktot, &lds[so + 3 * 8192 + tid * 16]);
    __builtin_amdgcn_s_setprio(1);
#pragma unroll
    for (int f = 0; f < 4; ++f)
#pragma unroll
      for (int g = 0; g < 4; ++g)
        acc[f][g] = __builtin_amdgcn_mfma_i32_16x16x64_i8(aE[f], b0v[g], acc[f][g], 0, 0, 0);
    __builtin_amdgcn_s_setprio(0);
    WAITVM(8);
    __builtin_amdgcn_s_barrier();

    // ---- P1: read P2 frags (A1/A3 k0 — gated by end-P0); MFMA. No barrier:
    //          P2's reads are of regions already gated by end-P0. ----
#pragma unroll
    for (int f = 0; f < 4; ++f) aE[f] = *(const i32x4*)&lds[bo + aOff + (f + 4) * 2048];
    __builtin_amdgcn_s_setprio(1);
#pragma unroll
    for (int f = 0; f < 4; ++f)
#pragma unroll
      for (int g = 0; g < 4; ++g)
        acc[f][g] = __builtin_amdgcn_mfma_i32_16x16x64_i8(aO[f], b1v[g], acc[f][g], 0, 0, 0);
    __builtin_amdgcn_s_setprio(0);

    // ---- P2: read P3 frags (A1/A3 k1 — same end-P0 gate); MFMA; WAITVM(2)
    //          [drains B0-3,A0,A2(t+1), 2-phase cover]; barrier (also the WAR
    //          fence: all waves done reading bo before anyone stages into it
    //          at P0(t+1)). ----
#pragma unroll
    for (int f = 0; f < 4; ++f) aO[f] = *(const i32x4*)&lds[bo + (aOff ^ 64) + (f + 4) * 2048];
    __builtin_amdgcn_s_setprio(1);
#pragma unroll
    for (int f = 0; f < 4; ++f)
#pragma unroll
      for (int g = 0; g < 4; ++g)
        acc[f + 4][g] = __builtin_amdgcn_mfma_i32_16x16x64_i8(aE[f], b0v[g], acc[f + 4][g], 0, 0, 0);
    __builtin_amdgcn_s_setprio(0);
    WAITVM(2);
    __builtin_amdgcn_s_barrier();

    // ---- P3: read NEXT-tile P0 frags from `so` (B/A0/A2 — gated by end-P2);
    //          MFMA. No barrier: next P0 only reads so-regions (same gate) and
    //          its GLD writes into bo are fenced by end-P2. ----
#pragma unroll
    for (int f = 0; f < 4; ++f) aE[f] = *(const i32x4*)&lds[so + aOff + f * 2048];
#pragma unroll
    for (int g = 0; g < 4; ++g) b0v[g] = *(const i32x4*)&lds[so + bOff + g * 2048];
    __builtin_amdgcn_s_setprio(1);
#pragma unroll
    for (int f = 0; f < 4; ++f)
#pragma unroll
      for (int g = 0; g < 4; ++g)
        acc[f + 4][g] = __builtin_amdgcn_mfma_i32_16x16x64_i8(aO[f], b1v[g], acc[f + 4][g], 0, 0, 0);
    __builtin_amdgcn_s_setprio(0);
  }

  // ---- Peeled last tile (t = NT-1): no staging; entry outstanding = A1,A3. ----
  {
    const int bo = ((NT - 1) & 1) * 32768;
    // P0
#pragma unroll
    for (int f = 0; f < 4; ++f) aO[f] = *(const i32x4*)&lds[bo + (aOff ^ 64) + f * 2048];
#pragma unroll
    for (int g = 0; g < 4; ++g) b1v[g] = *(const i32x4*)&lds[bo + (bOff ^ 64) + g * 2048];
    __builtin_amdgcn_s_setprio(1);
#pragma unroll
    for (int f = 0; f < 4; ++f)
#pragma unroll
      for (int g = 0; g < 4; ++g)
        acc[f][g] = __builtin_amdgcn_mfma_i32_16x16x64_i8(aE[f], b0v[g], acc[f][g], 0, 0, 0);
    __builtin_amdgcn_s_setprio(0);
    WAITVM(0);  // no staging this tile: full drain of A1,A3 before their reads
    __builtin_amdgcn_s_barrier();
    // P1
#pragma unroll
    for (int f = 0; f < 4; ++f) aE[f] = *(const i32x4*)&lds[bo + aOff + (f + 4) * 2048];
    __builtin_amdgcn_s_setprio(1);
#pragma unroll
    for (int f = 0; f < 4; ++f)
#pragma unroll
      for (int g = 0; g < 4; ++g)
        acc[f][g] = __builtin_amdgcn_mfma_i32_16x16x64_i8(aO[f], b1v[g], acc[f][g], 0, 0, 0);
    __builtin_amdgcn_s_setprio(0);
    // P2
#pragma unroll
    for (int f = 0; f < 4; ++f) aO[f] = *(const i32x4*)&lds[bo + (aOff ^ 64) + (f + 4) * 2048];
    __builtin_amdgcn_s_setprio(1);
#pragma unroll
    for (int f = 0; f < 4; ++f)
#pragma unroll
      for (int g = 0; g < 4; ++g)
        acc[f + 4][g] = __builtin_amdgcn_mfma_i32_16x16x64_i8(aE[f], b0v[g], acc[f + 4][g], 0, 0, 0);
    __builtin_amdgcn_s_setprio(0);
    // P3
    __builtin_amdgcn_s_setprio(1);
#pragma unroll
    for (int f = 0; f < 4; ++f)
#pragma unroll
      for (int g = 0; g < 4; ++g)
        acc[f + 4][g] = __builtin_amdgcn_mfma_i32_16x16x64_i8(aO[f], b1v[g], acc[f + 4][g], 0, 0, 0);
    __builtin_amdgcn_s_setprio(0);
  }

  // Epilogue: C/D layout col=lane&15, row=(lane>>4)*4+reg (HW-verified,
  // dtype-independent). y = acc * sx[m] * (SCB[n]/127).
  const int col = lane & 15;
  const int rbase = (lane >> 4) * 4;
#pragma unroll
  for (int f = 0; f < 8; ++f) {
    const int gmb = m0 + wm + f * 16 + rbase;
    float sm[4];
#pragma unroll
    for (int r = 0; r < 4; ++r) sm[r] = sx[gmb + r];
#pragma unroll
    for (int g = 0; g < 4; ++g) {
      const int gn = n0 + wn + g * 16 + col;
      const float snv = scb[gn] * (1.0f / 127.0f);
#pragma unroll
      for (int r = 0; r < 4; ++r)
        C[(size_t)(gmb + r) * Ntot + gn] = (float)acc[f][g][r] * sm[r] * snv;
    }
  }
}

// ---------------------------------------------------------------------------
extern "C" void kernel_launch(void* const* d_in, const int* in_sizes, int n_in,
                              void* d_out, int out_size, void* d_ws, size_t ws_size,
                              hipStream_t stream) {
  const float* x = (const float*)d_in[0];
  const int* CB32 = (const int*)d_in[1];  // harness: integer inputs -> const int*
  const float* SCB = (const float*)d_in[2];
  float* out = (float*)d_out;

  // ws layout: xq (32 MB) | cb8 (16 MB) | sx (32 KB)  => needs ~48.03 MB
  int8_t* xq = (int8_t*)d_ws;
  int8_t* cb8 = (int8_t*)d_ws + (size_t)Mtot * Ktot;
  float* sx = (float*)((int8_t*)d_ws + (size_t)Mtot * Ktot + (size_t)Ntot * Ktot);

  // fused prep: 16384 pack blocks + 8192 quant blocks
  prep_kernel<<<16384 + Mtot, 256, 0, stream>>>(CB32, cb8, x, xq, sx);
  // 256x256 tiles: (8192/256) * (4096/256) = 32*16 = 512 WGs (flattened, XCD-swizzled)
  gemm_i8_kernel<<<512, 512, 0, stream>>>(xq, cb8, sx, SCB, out);
}